// Round 1
// baseline (267.971 us; speedup 1.0000x reference)
//
#include <hip/hip_runtime.h>
#include <hip/hip_bf16.h>
#include <cstdint>

typedef __attribute__((ext_vector_type(8))) short bf16x8;
typedef __attribute__((ext_vector_type(4))) float f32x4;

#define LDT 72  // padded LDS row stride (bf16 elems): 144B = 16B-aligned, bank stride 36%32=4 -> 2-way max

static __device__ __forceinline__ unsigned short f2bf(float x) {
    union { float f; uint32_t u; } v; v.f = x;
    uint32_t r = v.u + 0x7FFFu + ((v.u >> 16) & 1u);
    return (unsigned short)(r >> 16);
}
static __device__ __forceinline__ float bf2f(unsigned short b) {
    union { float f; uint32_t u; } v; v.u = ((uint32_t)b) << 16;
    return v.f;
}

// ---------------------------------------------------------------------------
// Projection GEMM: Y[m][e] = sum_k X[m][k] * W[e][k] + bias[e]
// M = B*S = 4096, N = 1024, K = 1024.  Output bf16 in (B, H, S, 64) layout.
// 128x128 tile, BK=64, 256 threads (4 waves, each 64x64 of the tile).
// ---------------------------------------------------------------------------
__global__ __launch_bounds__(256) void proj_gemm(const float* __restrict__ X,
                                                 const float* __restrict__ W,
                                                 const float* __restrict__ bias,
                                                 unsigned short* __restrict__ dst) {
    __shared__ unsigned short a_lds[128 * LDT];
    __shared__ unsigned short b_lds[128 * LDT];

    const int tid = threadIdx.x;
    const int lane = tid & 63;
    const int w = tid >> 6;
    const int lr = lane & 15;
    const int lg = lane >> 4;
    const int m0 = blockIdx.x * 128;
    const int e0 = blockIdx.y * 128;
    const int wrow = (w >> 1) * 64;
    const int wcol = (w & 1) * 64;

    f32x4 acc[4][4] = {};

    for (int k0 = 0; k0 < 1024; k0 += 64) {
        __syncthreads();
        // stage 128x64 fp32 of X and W, convert to bf16. 2048 float4 each; 8/thread.
        for (int i = 0; i < 8; ++i) {
            int f = tid + 256 * i;          // 0..2047
            int row = f >> 4;               // 16 float4 per row
            int c4 = (f & 15) << 2;         // col (floats)
            float4 xa = *(const float4*)(X + (size_t)(m0 + row) * 1024 + k0 + c4);
            ushort4 pa;
            pa.x = f2bf(xa.x); pa.y = f2bf(xa.y); pa.z = f2bf(xa.z); pa.w = f2bf(xa.w);
            *(ushort4*)(a_lds + row * LDT + c4) = pa;
            float4 xb = *(const float4*)(W + (size_t)(e0 + row) * 1024 + k0 + c4);
            ushort4 pb;
            pb.x = f2bf(xb.x); pb.y = f2bf(xb.y); pb.z = f2bf(xb.z); pb.w = f2bf(xb.w);
            *(ushort4*)(b_lds + row * LDT + c4) = pb;
        }
        __syncthreads();

        for (int ks = 0; ks < 2; ++ks) {
            const int kk = ks * 32 + lg * 8;
            bf16x8 af[4], bfr[4];
            for (int mt = 0; mt < 4; ++mt)
                af[mt] = *(const bf16x8*)(a_lds + (wrow + mt * 16 + lr) * LDT + kk);
            for (int nt = 0; nt < 4; ++nt)
                bfr[nt] = *(const bf16x8*)(b_lds + (wcol + nt * 16 + lr) * LDT + kk);
            for (int mt = 0; mt < 4; ++mt)
                for (int nt = 0; nt < 4; ++nt)
                    acc[mt][nt] = __builtin_amdgcn_mfma_f32_16x16x32_bf16(
                        af[mt], bfr[nt], acc[mt][nt], 0, 0, 0);
        }
    }

    // epilogue: C/D layout col = lane&15, row = (lane>>4)*4 + i  [m89-verified]
    for (int mt = 0; mt < 4; ++mt)
        for (int nt = 0; nt < 4; ++nt)
            for (int i = 0; i < 4; ++i) {
                int m = m0 + wrow + mt * 16 + lg * 4 + i;  // row of X (b,s)
                int e = e0 + wcol + nt * 16 + lr;          // output feature
                float val = acc[mt][nt][i] + bias[e];
                int b = m >> 11, s = m & 2047;
                int h = e >> 6, d = e & 63;
                dst[(((size_t)b * 16 + h) * 2048 + s) * 64 + d] = f2bf(val);
            }
}

// ---------------------------------------------------------------------------
// Flash attention: one block = 64 Q rows of one (b,h). 4 waves x 16 rows.
// K staged row-major [64][LDT]; V staged transposed [d][kv]; P via per-wave LDS.
// Softmax in exp2 domain; 0.125*log2(e) folded into Q fragments.
// ---------------------------------------------------------------------------
__global__ __launch_bounds__(256) void attn_kernel(const unsigned short* __restrict__ Qh,
                                                   const unsigned short* __restrict__ Kh,
                                                   const unsigned short* __restrict__ Vh,
                                                   const unsigned char* __restrict__ mask,
                                                   float* __restrict__ Out) {
    __shared__ unsigned short k_lds[64 * LDT];
    __shared__ unsigned short v_lds[64 * LDT];      // transposed: [d][kv]
    __shared__ unsigned short p_lds[4][16 * LDT];   // per-wave P tile [q][kv]

    const int tid = threadIdx.x;
    const int lane = tid & 63;
    const int w = tid >> 6;
    const int lr = lane & 15;
    const int lg = lane >> 4;
    const int q0 = blockIdx.x * 64;
    const int h = blockIdx.y;
    const int b = blockIdx.z;

    const size_t headoff = (((size_t)b * 16) + h) * 2048 * 64;
    const unsigned short* Qp = Qh + headoff;
    const unsigned short* Kp = Kh + headoff;
    const unsigned short* Vp = Vh + headoff;

    // Q fragments (A operand): row = lane&15, k = (lane>>4)*8 + j (+32 per ks)
    const float qscale = 0.125f * 1.44269504088896340736f;  // 1/sqrt(64) * log2(e)
    bf16x8 qf[2];
    {
        int row = q0 + w * 16 + lr;
        for (int ks = 0; ks < 2; ++ks) {
            bf16x8 t = *(const bf16x8*)(Qp + (size_t)row * 64 + ks * 32 + lg * 8);
            for (int j = 0; j < 8; ++j)
                t[j] = (short)f2bf(bf2f((unsigned short)t[j]) * qscale);
            qf[ks] = t;
        }
    }

    f32x4 o[4] = {};
    float mrow[4], lsum[4];
    for (int i = 0; i < 4; ++i) { mrow[i] = -INFINITY; lsum[i] = 0.f; }

    for (int t = 0; t < 32; ++t) {
        const int kv0 = t * 64;
        __syncthreads();
        // stage K row-major + V transposed. 512 16B-chunks per matrix; 2/thread.
        for (int i = 0; i < 2; ++i) {
            int c = tid + 256 * i;
            int row = c >> 3;
            int off = (c & 7) * 8;
            *(uint4*)(k_lds + row * LDT + off) =
                *(const uint4*)(Kp + (size_t)(kv0 + row) * 64 + off);
            uint4 vv = *(const uint4*)(Vp + (size_t)(kv0 + row) * 64 + off);
            const unsigned short* pv = (const unsigned short*)&vv;
            for (int j = 0; j < 8; ++j)
                v_lds[(off + j) * LDT + row] = pv[j];
        }
        __syncthreads();

        // scores: S^(log2-domain)[q][kv], acc layout col=kv=lane&15+16nt, row=q=(lane>>4)*4+i
        f32x4 s[4] = {};
        for (int ks = 0; ks < 2; ++ks) {
            const int kk = ks * 32 + lg * 8;
            for (int nt = 0; nt < 4; ++nt) {
                bf16x8 kf = *(const bf16x8*)(k_lds + (nt * 16 + lr) * LDT + kk);
                s[nt] = __builtin_amdgcn_mfma_f32_16x16x32_bf16(qf[ks], kf, s[nt], 0, 0, 0);
            }
        }
        // mask (column-wise)
        for (int nt = 0; nt < 4; ++nt)
            if (mask[b * 2048 + kv0 + nt * 16 + lr])
                for (int i = 0; i < 4; ++i) s[nt][i] = -1e30f;

        // online softmax (rows owned by this lane: (lane>>4)*4 + i)
        float pf[4][4];
        for (int i = 0; i < 4; ++i) {
            float mx = fmaxf(fmaxf(s[0][i], s[1][i]), fmaxf(s[2][i], s[3][i]));
            mx = fmaxf(mx, __shfl_xor(mx, 1));
            mx = fmaxf(mx, __shfl_xor(mx, 2));
            mx = fmaxf(mx, __shfl_xor(mx, 4));
            mx = fmaxf(mx, __shfl_xor(mx, 8));
            float nm = fmaxf(mrow[i], mx);
            float f = exp2f(mrow[i] - nm);
            mrow[i] = nm;
            float ls = 0.f;
            for (int nt = 0; nt < 4; ++nt) {
                float p = exp2f(s[nt][i] - nm);
                pf[nt][i] = p;
                ls += p;
            }
            ls += __shfl_xor(ls, 1);
            ls += __shfl_xor(ls, 2);
            ls += __shfl_xor(ls, 4);
            ls += __shfl_xor(ls, 8);
            lsum[i] = lsum[i] * f + ls;
            for (int nt = 0; nt < 4; ++nt) o[nt][i] *= f;
        }

        // P -> per-wave LDS (acc layout -> row-major [q][kv])
        for (int nt = 0; nt < 4; ++nt)
            for (int i = 0; i < 4; ++i)
                p_lds[w][(lg * 4 + i) * LDT + nt * 16 + lr] = f2bf(pf[nt][i]);

        // PV: O += P @ V.  A-frag from p_lds (row=lane&15), B-frag from v_lds (col=lane&15)
        for (int ks = 0; ks < 2; ++ks) {
            const int kk = ks * 32 + lg * 8;
            bf16x8 pfr = *(const bf16x8*)(&p_lds[w][lr * LDT + kk]);
            for (int nt = 0; nt < 4; ++nt) {
                bf16x8 vf = *(const bf16x8*)(v_lds + (nt * 16 + lr) * LDT + kk);
                o[nt] = __builtin_amdgcn_mfma_f32_16x16x32_bf16(pfr, vf, o[nt], 0, 0, 0);
            }
        }
    }

    // epilogue: out[b][s][h*64+d] fp32
    for (int nt = 0; nt < 4; ++nt)
        for (int i = 0; i < 4; ++i) {
            int s_idx = q0 + w * 16 + lg * 4 + i;
            int d = nt * 16 + lr;
            Out[((size_t)b * 2048 + s_idx) * 1024 + h * 64 + d] = o[nt][i] / lsum[i];
        }
}

extern "C" void kernel_launch(void* const* d_in, const int* in_sizes, int n_in,
                              void* d_out, int out_size, void* d_ws, size_t ws_size,
                              hipStream_t stream) {
    const float* v = (const float*)d_in[0];
    const float* k = (const float*)d_in[1];
    const float* q = (const float*)d_in[2];
    const unsigned char* mask = (const unsigned char*)d_in[3];
    const float* Wq = (const float*)d_in[4];
    const float* bq = (const float*)d_in[5];
    const float* Wk = (const float*)d_in[6];
    const float* bk = (const float*)d_in[7];
    const float* Wv = (const float*)d_in[8];
    const float* bv = (const float*)d_in[9];
    float* out = (float*)d_out;

    unsigned short* qws = (unsigned short*)d_ws;
    unsigned short* kws = qws + 4194304;  // 2*16*2048*64
    unsigned short* vws = kws + 4194304;

    dim3 pgrid(32, 8, 1);
    proj_gemm<<<pgrid, 256, 0, stream>>>(q, Wq, bq, qws);
    proj_gemm<<<pgrid, 256, 0, stream>>>(k, Wk, bk, kws);
    proj_gemm<<<pgrid, 256, 0, stream>>>(v, Wv, bv, vws);

    dim3 agrid(32, 16, 2);
    attn_kernel<<<agrid, 256, 0, stream>>>(qws, kws, vws, mask, out);
}